// Round 2
// baseline (216.143 us; speedup 1.0000x reference)
//
#include <hip/hip_runtime.h>
#include <hip/hip_bf16.h>
#include <math.h>

#define T_TOKENS 16384
#define DDIM 2048
#define NEXP 64
#define TOKS_PER_WAVE 8
#define WAVES_PER_BLOCK 4
#define TOKS_PER_BLOCK (TOKS_PER_WAVE * WAVES_PER_BLOCK)   // 32
#define CHUNK_D 128
#define NCHUNK (DDIM / CHUNK_D)                            // 16
#define LDS_STRIDE 132                                     // 128 + 4 pad; rows stay 16B-aligned
#define REFINE_TAU 1e-3f

__device__ __forceinline__ bool better(double va, int ia, double vb, int ib) {
    return (va > vb) || (va == vb && ia < ib);
}

// f64 wave-cooperative dot of x-row and W-row (only on the rare near-tie path)
__device__ __forceinline__ double dot_f64(const float* __restrict__ xrow,
                                          const float* __restrict__ wr,
                                          int lane) {
    double sd = 0.0;
    for (int d = lane; d < DDIM; d += 64)
        sd = fma((double)xrow[d], (double)wr[d], sd);
#pragma unroll
    for (int off = 32; off >= 1; off >>= 1) sd += __shfl_xor(sd, off);
    return sd;
}

__global__ __launch_bounds__(256, 2)
void moe_router_kernel(const float* __restrict__ x,
                       const float* __restrict__ W,
                       float* __restrict__ out) {
    __shared__ float wlds[NEXP * LDS_STRIDE];

    const int tid  = threadIdx.x;
    const int lane = tid & 63;
    const int wave = __builtin_amdgcn_readfirstlane(tid >> 6);  // force SGPR -> uniform x addrs
    const int tok0 = blockIdx.x * TOKS_PER_BLOCK + wave * TOKS_PER_WAVE;

    float4 acc[TOKS_PER_WAVE];
#pragma unroll
    for (int t = 0; t < TOKS_PER_WAVE; ++t) acc[t] = make_float4(0.f, 0.f, 0.f, 0.f);

    // staging map: thread -> (row e, quad q): 2 contiguous 512B rows per wave -> coalesced
    const int se = tid >> 5;   // 0..7
    const int sq = tid & 31;   // 0..31

    const float* __restrict__ xbase = x + (size_t)tok0 * DDIM;

    for (int c = 0; c < NCHUNK; ++c) {
        const int d0 = c * CHUNK_D;

        // ---- stage W[0:64][d0:d0+128] -> LDS [64][132] ----
#pragma unroll
        for (int p = 0; p < 8; ++p) {
            const int e = se + p * 8;
            const float4 v = *reinterpret_cast<const float4*>(
                &W[(size_t)e * DDIM + d0 + sq * 4]);
            *reinterpret_cast<float4*>(&wlds[e * LDS_STRIDE + sq * 4]) = v;
        }
        __syncthreads();

        // ---- broadcast-FMA main loop (all indices compile-time) ----
        const float4* __restrict__ wrow =
            reinterpret_cast<const float4*>(&wlds[lane * LDS_STRIDE]);
#pragma unroll 4
        for (int q = 0; q < CHUNK_D / 4; ++q) {
            const float4 wv = wrow[q];           // per-lane ds_read_b128
#pragma unroll
            for (int t = 0; t < TOKS_PER_WAVE; ++t) {
                // wave-uniform address -> scalar load (broadcast x over the 64 expert-lanes)
                const float4 xv = *reinterpret_cast<const float4*>(
                    &xbase[t * DDIM + d0 + q * 4]);
                acc[t].x = fmaf(xv.x, wv.x, acc[t].x);
                acc[t].y = fmaf(xv.y, wv.y, acc[t].y);
                acc[t].z = fmaf(xv.z, wv.z, acc[t].z);
                acc[t].w = fmaf(xv.w, wv.w, acc[t].w);
            }
        }
        __syncthreads();
    }

    // ---- epilogue: per token, lane e holds logit[e]; softmax + top-2 across lanes ----
    // FULLY UNROLLED over t so acc[t] stays compile-time-indexed (no scratch).
    float* __restrict__ outw = out;                              // [T][2] weights
    float* __restrict__ outi = out + (size_t)T_TOKENS * 2;       // [T][2] indices (as float)

#pragma unroll
    for (int t = 0; t < TOKS_PER_WAVE; ++t) {
        const float l = (acc[t].x + acc[t].y) + (acc[t].z + acc[t].w);

        // top-1 (argmax, ties -> lower index, matches lax.top_k)
        float v1 = l; int i1 = lane;
#pragma unroll
        for (int off = 32; off >= 1; off >>= 1) {
            const float ov = __shfl_xor(v1, off);
            const int   oi = __shfl_xor(i1, off);
            if (ov > v1 || (ov == v1 && oi < i1)) { v1 = ov; i1 = oi; }
        }
        // top-2
        float v2 = (lane == i1) ? -INFINITY : l; int i2 = lane;
#pragma unroll
        for (int off = 32; off >= 1; off >>= 1) {
            const float ov = __shfl_xor(v2, off);
            const int   oi = __shfl_xor(i2, off);
            if (ov > v2 || (ov == v2 && oi < i2)) { v2 = ov; i2 = oi; }
        }
        // top-3 (candidate for refinement)
        float v3 = (lane == i1 || lane == i2) ? -INFINITY : l; int i3 = lane;
#pragma unroll
        for (int off = 32; off >= 1; off >>= 1) {
            const float ov = __shfl_xor(v3, off);
            const int   oi = __shfl_xor(i3, off);
            if (ov > v3 || (ov == v3 && oi < i3)) { v3 = ov; i3 = oi; }
        }

        // softmax pieces (order-invariant in the final ratio)
        const float p = expf(l - v1);
        float s = p;
#pragma unroll
        for (int off = 32; off >= 1; off >>= 1) s += __shfl_xor(s, off);

        int iA = i1, iB = i2;
        // near-tie -> recompute 3 candidate logits in f64, re-rank (rare, wave-uniform).
        // Named scalars only: no runtime-indexed arrays -> no scratch.
        if ((v1 - v2) < REFINE_TAU || (v2 - v3) < REFINE_TAU) {
            const float* __restrict__ xrow = x + (size_t)(tok0 + t) * DDIM;
            double La = dot_f64(xrow, W + (size_t)i1 * DDIM, lane);
            double Lb = dot_f64(xrow, W + (size_t)i2 * DDIM, lane);
            double Lc = dot_f64(xrow, W + (size_t)i3 * DDIM, lane);
            int ia = i1, ib = i2, ic = i3;
            if (!better(La, ia, Lb, ib)) { double tv = La; La = Lb; Lb = tv; int ti = ia; ia = ib; ib = ti; }
            if (!better(Lb, ib, Lc, ic)) { double tv = Lb; Lb = Lc; Lc = tv; int ti = ib; ib = ic; ic = ti; }
            if (!better(La, ia, Lb, ib)) { double tv = La; La = Lb; Lb = tv; int ti = ia; ia = ib; ib = ti; }
            iA = ia; iB = ib;
        }

        const float pA = __shfl(p, iA);
        const float pB = __shfl(p, iB);
        const float pa = pA / s;
        const float pb = pB / s;
        const float inv = 1.0f / (pa + pb + 1e-9f);

        if (lane == 0) {
            const size_t tg = (size_t)(tok0 + t);
            outw[tg * 2]     = pa * inv;
            outw[tg * 2 + 1] = pb * inv;
            outi[tg * 2]     = (float)iA;
            outi[tg * 2 + 1] = (float)iB;
        }
    }
}

extern "C" void kernel_launch(void* const* d_in, const int* in_sizes, int n_in,
                              void* d_out, int out_size, void* d_ws, size_t ws_size,
                              hipStream_t stream) {
    const float* x = (const float*)d_in[0];
    const float* W = (const float*)d_in[1];
    float* out = (float*)d_out;
    const int grid = T_TOKENS / TOKS_PER_BLOCK;  // 512 blocks x 256 threads = 2048 waves
    moe_router_kernel<<<grid, 256, 0, stream>>>(x, W, out);
}

// Round 3
// 160.745 us; speedup vs baseline: 1.3446x; 1.3446x over previous
//
#include <hip/hip_runtime.h>
#include <hip/hip_bf16.h>
#include <math.h>

#define T_TOKENS 16384
#define DDIM 2048
#define NEXP 64
#define TOKS_PER_WAVE 8
#define WAVES_PER_BLOCK 4
#define TOKS_PER_BLOCK (TOKS_PER_WAVE * WAVES_PER_BLOCK)   // 32
#define CHUNK_D 128
#define NCHUNK (DDIM / CHUNK_D)                            // 16
#define LDS_STRIDE 132                                     // W rows: 128 + 4 pad, 16B-aligned
#define REFINE_TAU 1e-3f

__device__ __forceinline__ bool better(double va, int ia, double vb, int ib) {
    return (va > vb) || (va == vb && ia < ib);
}

// f64 wave-cooperative dot (rare near-tie path only)
__device__ __forceinline__ double dot_f64(const float* __restrict__ xrow,
                                          const float* __restrict__ wr,
                                          int lane) {
    double sd = 0.0;
    for (int d = lane; d < DDIM; d += 64)
        sd = fma((double)xrow[d], (double)wr[d], sd);
#pragma unroll
    for (int off = 32; off >= 1; off >>= 1) sd += __shfl_xor(sd, off);
    return sd;
}

__global__ __launch_bounds__(256, 2)
void moe_router_kernel(const float* __restrict__ x,
                       const float* __restrict__ W,
                       float* __restrict__ out) {
    __shared__ float wlds[NEXP * LDS_STRIDE];            // 33 KB
    __shared__ float xlds[TOKS_PER_BLOCK * CHUNK_D];     // 16 KB

    const int tid  = threadIdx.x;
    const int lane = tid & 63;
    const int wave = tid >> 6;
    const int tokb = blockIdx.x * TOKS_PER_BLOCK;

    float4 acc[TOKS_PER_WAVE];
#pragma unroll
    for (int t = 0; t < TOKS_PER_WAVE; ++t) acc[t] = make_float4(0.f, 0.f, 0.f, 0.f);

    // W staging map: thread -> (expert row, quad)
    const int se = tid >> 5;   // 0..7
    const int sq = tid & 31;   // 0..31
    // x staging map: half-wave covers one full 512B row
    const int xr = tid >> 5;   // 0..7  (row group)
    const int xq = tid & 31;   // 0..31 (float4 within row)

    for (int c = 0; c < NCHUNK; ++c) {
        const int d0 = c * CHUNK_D;

        // ---- stage W[0:64][d0:d0+128] -> LDS [64][132] ----
#pragma unroll
        for (int p = 0; p < 8; ++p) {
            const int e = se + p * 8;
            const float4 v = *reinterpret_cast<const float4*>(
                &W[(size_t)e * DDIM + d0 + sq * 4]);
            *reinterpret_cast<float4*>(&wlds[e * LDS_STRIDE + sq * 4]) = v;
        }
        // ---- stage x[tokb:tokb+32][d0:d0+128] -> LDS [32][128] ----
#pragma unroll
        for (int p = 0; p < 4; ++p) {
            const int r = xr + p * 8;
            const float4 v = *reinterpret_cast<const float4*>(
                &x[(size_t)(tokb + r) * DDIM + d0 + xq * 4]);
            *reinterpret_cast<float4*>(&xlds[r * CHUNK_D + xq * 4]) = v;
        }
        __syncthreads();

        // ---- broadcast-FMA main loop: W per-lane, x via LDS broadcast ----
        const float4* __restrict__ wrow =
            reinterpret_cast<const float4*>(&wlds[lane * LDS_STRIDE]);
        const float4* __restrict__ xrow =
            reinterpret_cast<const float4*>(&xlds[wave * TOKS_PER_WAVE * CHUNK_D]);
#pragma unroll 4
        for (int q = 0; q < CHUNK_D / 4; ++q) {
            const float4 wv = wrow[q];               // per-lane ds_read_b128
#pragma unroll
            for (int t = 0; t < TOKS_PER_WAVE; ++t) {
                const float4 xv = xrow[t * (CHUNK_D / 4) + q];  // uniform ds_read_b128 (broadcast)
                acc[t].x = fmaf(xv.x, wv.x, acc[t].x);
                acc[t].y = fmaf(xv.y, wv.y, acc[t].y);
                acc[t].z = fmaf(xv.z, wv.z, acc[t].z);
                acc[t].w = fmaf(xv.w, wv.w, acc[t].w);
            }
        }
        __syncthreads();
    }

    // ---- epilogue: lane e holds logit[e]; softmax + top-2 across lanes ----
    float* __restrict__ outw = out;                              // [T][2] weights
    float* __restrict__ outi = out + (size_t)T_TOKENS * 2;       // [T][2] indices (as float)
    const int tok0 = tokb + wave * TOKS_PER_WAVE;

#pragma unroll
    for (int t = 0; t < TOKS_PER_WAVE; ++t) {
        const float l = (acc[t].x + acc[t].y) + (acc[t].z + acc[t].w);

        // top-1 (ties -> lower index, matches lax.top_k)
        float v1 = l; int i1 = lane;
#pragma unroll
        for (int off = 32; off >= 1; off >>= 1) {
            const float ov = __shfl_xor(v1, off);
            const int   oi = __shfl_xor(i1, off);
            if (ov > v1 || (ov == v1 && oi < i1)) { v1 = ov; i1 = oi; }
        }
        // top-2
        float v2 = (lane == i1) ? -INFINITY : l; int i2 = lane;
#pragma unroll
        for (int off = 32; off >= 1; off >>= 1) {
            const float ov = __shfl_xor(v2, off);
            const int   oi = __shfl_xor(i2, off);
            if (ov > v2 || (ov == v2 && oi < i2)) { v2 = ov; i2 = oi; }
        }
        // top-3 (refinement candidate)
        float v3 = (lane == i1 || lane == i2) ? -INFINITY : l; int i3 = lane;
#pragma unroll
        for (int off = 32; off >= 1; off >>= 1) {
            const float ov = __shfl_xor(v3, off);
            const int   oi = __shfl_xor(i3, off);
            if (ov > v3 || (ov == v3 && oi < i3)) { v3 = ov; i3 = oi; }
        }

        const float p = expf(l - v1);
        float s = p;
#pragma unroll
        for (int off = 32; off >= 1; off >>= 1) s += __shfl_xor(s, off);

        int iA = i1, iB = i2;
        // near-tie -> f64 recompute of 3 candidates, re-rank (wave-uniform, rare)
        if ((v1 - v2) < REFINE_TAU || (v2 - v3) < REFINE_TAU) {
            const float* __restrict__ xrow2 = x + (size_t)(tok0 + t) * DDIM;
            double La = dot_f64(xrow2, W + (size_t)i1 * DDIM, lane);
            double Lb = dot_f64(xrow2, W + (size_t)i2 * DDIM, lane);
            double Lc = dot_f64(xrow2, W + (size_t)i3 * DDIM, lane);
            int ia = i1, ib = i2, ic = i3;
            if (!better(La, ia, Lb, ib)) { double tv = La; La = Lb; Lb = tv; int ti = ia; ia = ib; ib = ti; }
            if (!better(Lb, ib, Lc, ic)) { double tv = Lb; Lb = Lc; Lc = tv; int ti = ib; ib = ic; ic = ti; }
            if (!better(La, ia, Lb, ib)) { double tv = La; La = Lb; Lb = tv; int ti = ia; ia = ib; ib = ti; }
            iA = ia; iB = ib;
        }

        const float pA = __shfl(p, iA);
        const float pB = __shfl(p, iB);
        const float pa = pA / s;
        const float pb = pB / s;
        const float inv = 1.0f / (pa + pb + 1e-9f);

        if (lane == 0) {
            const size_t tg = (size_t)(tok0 + t);
            outw[tg * 2]     = pa * inv;
            outw[tg * 2 + 1] = pb * inv;
            outi[tg * 2]     = (float)iA;
            outi[tg * 2 + 1] = (float)iB;
        }
    }
}

extern "C" void kernel_launch(void* const* d_in, const int* in_sizes, int n_in,
                              void* d_out, int out_size, void* d_ws, size_t ws_size,
                              hipStream_t stream) {
    const float* x = (const float*)d_in[0];
    const float* W = (const float*)d_in[1];
    float* out = (float*)d_out;
    const int grid = T_TOKENS / TOKS_PER_BLOCK;  // 512 blocks x 256 threads
    moe_router_kernel<<<grid, 256, 0, stream>>>(x, W, out);
}

// Round 4
// 107.731 us; speedup vs baseline: 2.0063x; 1.4921x over previous
//
#include <hip/hip_runtime.h>
#include <hip/hip_bf16.h>
#include <math.h>

#define T_TOKENS 16384
#define DDIM 2048
#define NEXP 64
#define KC 64
#define NCH (DDIM / KC)          // 32 K-chunks
#define BLK_TOK 32               // tokens per block (kernel 1)
#define REFINE_TAU 4e-3f

typedef short bf16x8 __attribute__((ext_vector_type(8)));
typedef float f32x4 __attribute__((ext_vector_type(4)));

__device__ __forceinline__ short bf16hi(float f) {
    __hip_bfloat16 h = __float2bfloat16(f);       // RNE
    return *reinterpret_cast<short*>(&h);
}
__device__ __forceinline__ float bf16up(short s) {
    __hip_bfloat16 h = *reinterpret_cast<__hip_bfloat16*>(&s);
    return __bfloat162float(h);
}

// ---------------- Kernel 1: split-bf16 MFMA gate GEMM -> fp32 logits ----------------
// block: 256 thr = 4 waves; tile 32 tok x 64 exp; wave = 16 tok x 32 exp.
// LDS (single 24 KB buffer, shorts): XH[32][64] @0, XL @2048, WH[64][64] @4096, WL @8192
// swizzle: byte ^= ((row&7)<<4)  (rows are 128 B; kills the stride-128B bank conflict)
__global__ __launch_bounds__(256, 2)
void gate_gemm(const float* __restrict__ x,
               const float* __restrict__ W,
               float* __restrict__ logits) {
    __shared__ short lds[12288];

    const int tid  = threadIdx.x;
    const int lane = tid & 63;
    const int wv   = tid >> 6;
    const int tg   = wv >> 1;          // token group (0..1) -> 16 tokens
    const int eg   = wv & 1;           // expert group (0..1) -> 32 experts
    const int tokb = blockIdx.x * BLK_TOK;

    // staging maps
    const int xrow = tid >> 3;                 // 0..31, x token row
    const int xk   = (tid & 7) * 8;            // float index in row (8 floats/thread)
    const int wrow = tid >> 2;                 // 0..63, W expert row
    const int wk   = (tid & 3) * 16;           // 16 floats/thread

    f32x4 acc[2];
#pragma unroll
    for (int n = 0; n < 2; ++n) acc[n] = (f32x4){0.f, 0.f, 0.f, 0.f};

    float4 gx0, gx1, gw0, gw1, gw2, gw3;

    // prologue: issue chunk 0 loads
    {
        const float* xp = &x[(size_t)(tokb + xrow) * DDIM + xk];
        gx0 = *(const float4*)(xp);
        gx1 = *(const float4*)(xp + 4);
        const float* wp = &W[(size_t)wrow * DDIM + wk];
        gw0 = *(const float4*)(wp);
        gw1 = *(const float4*)(wp + 4);
        gw2 = *(const float4*)(wp + 8);
        gw3 = *(const float4*)(wp + 12);
    }

    for (int c = 0; c < NCH; ++c) {
        // ---- commit staged regs -> LDS (convert to bf16 hi/lo) ----
        {
            float fx[8] = { gx0.x, gx0.y, gx0.z, gx0.w, gx1.x, gx1.y, gx1.z, gx1.w };
            bf16x8 hx, lx;
#pragma unroll
            for (int j = 0; j < 8; ++j) {
                const short h = bf16hi(fx[j]);
                hx[j] = h;
                lx[j] = bf16hi(fx[j] - bf16up(h));
            }
            const int xb = (xrow * 128 + xk * 2) ^ ((xrow & 7) << 4);
            *(bf16x8*)((char*)&lds[0]    + xb) = hx;
            *(bf16x8*)((char*)&lds[2048] + xb) = lx;

            float fw[16] = { gw0.x, gw0.y, gw0.z, gw0.w, gw1.x, gw1.y, gw1.z, gw1.w,
                             gw2.x, gw2.y, gw2.z, gw2.w, gw3.x, gw3.y, gw3.z, gw3.w };
#pragma unroll
            for (int g = 0; g < 2; ++g) {
                bf16x8 hw, lw;
#pragma unroll
                for (int j = 0; j < 8; ++j) {
                    const float f = fw[g * 8 + j];
                    const short h = bf16hi(f);
                    hw[j] = h;
                    lw[j] = bf16hi(f - bf16up(h));
                }
                const int wb = (wrow * 128 + (wk + g * 8) * 2) ^ ((wrow & 7) << 4);
                *(bf16x8*)((char*)&lds[4096] + wb) = hw;
                *(bf16x8*)((char*)&lds[8192] + wb) = lw;
            }
        }
        __syncthreads();

        // ---- issue next chunk's global loads (fly during MFMA phase) ----
        if (c + 1 < NCH) {
            const int d0 = (c + 1) * KC;
            const float* xp = &x[(size_t)(tokb + xrow) * DDIM + d0 + xk];
            gx0 = *(const float4*)(xp);
            gx1 = *(const float4*)(xp + 4);
            const float* wp = &W[(size_t)wrow * DDIM + d0 + wk];
            gw0 = *(const float4*)(wp);
            gw1 = *(const float4*)(wp + 4);
            gw2 = *(const float4*)(wp + 8);
            gw3 = *(const float4*)(wp + 12);
        }

        // ---- compute: 2 K-steps x (1 M x 2 N) x 3 split-MFMAs ----
#pragma unroll
        for (int ks = 0; ks < 2; ++ks) {
            const int kb = ks * 64 + (lane >> 4) * 16;        // byte offset in row
            const int ar = tg * 16 + (lane & 15);
            const int ab = (ar * 128 + kb) ^ ((ar & 7) << 4);
            const bf16x8 ah = *(const bf16x8*)((char*)&lds[0]    + ab);
            const bf16x8 al = *(const bf16x8*)((char*)&lds[2048] + ab);
#pragma unroll
            for (int n = 0; n < 2; ++n) {
                const int br = eg * 32 + n * 16 + (lane & 15);
                const int bb = (br * 128 + kb) ^ ((br & 7) << 4);
                const bf16x8 bh = *(const bf16x8*)((char*)&lds[4096] + bb);
                const bf16x8 bl = *(const bf16x8*)((char*)&lds[8192] + bb);
                acc[n] = __builtin_amdgcn_mfma_f32_16x16x32_bf16(ah, bh, acc[n], 0, 0, 0);
                acc[n] = __builtin_amdgcn_mfma_f32_16x16x32_bf16(ah, bl, acc[n], 0, 0, 0);
                acc[n] = __builtin_amdgcn_mfma_f32_16x16x32_bf16(al, bh, acc[n], 0, 0, 0);
            }
        }
        __syncthreads();
    }

    // ---- C write: col=lane&15, row=(lane>>4)*4+j (m89-verified mapping) ----
#pragma unroll
    for (int n = 0; n < 2; ++n) {
#pragma unroll
        for (int j = 0; j < 4; ++j) {
            const int token  = tokb + tg * 16 + ((lane >> 4) << 2) + j;
            const int expert = eg * 32 + n * 16 + (lane & 15);
            logits[(size_t)token * NEXP + expert] = acc[n][j];
        }
    }
}

// ---------------- Kernel 2: softmax + top-2 epilogue (verified structure) ----------------
__device__ __forceinline__ bool better(double va, int ia, double vb, int ib) {
    return (va > vb) || (va == vb && ia < ib);
}

__device__ __forceinline__ double dot_f64(const float* __restrict__ xrow,
                                          const float* __restrict__ wr,
                                          int lane) {
    double sd = 0.0;
    for (int d = lane; d < DDIM; d += 64)
        sd = fma((double)xrow[d], (double)wr[d], sd);
#pragma unroll
    for (int off = 32; off >= 1; off >>= 1) sd += __shfl_xor(sd, off);
    return sd;
}

__global__ __launch_bounds__(256, 4)
void router_epilogue(const float* __restrict__ logits,
                     const float* __restrict__ x,
                     const float* __restrict__ W,
                     float* __restrict__ out) {
    const int tid  = threadIdx.x;
    const int lane = tid & 63;
    const int wave = tid >> 6;
    const int tok0 = (blockIdx.x * 4 + wave) * 8;

    float* __restrict__ outw = out;
    float* __restrict__ outi = out + (size_t)T_TOKENS * 2;

#pragma unroll 1
    for (int t = 0; t < 8; ++t) {
        const int tok = tok0 + t;
        const float l = logits[(size_t)tok * NEXP + lane];

        float v1 = l; int i1 = lane;
#pragma unroll
        for (int off = 32; off >= 1; off >>= 1) {
            const float ov = __shfl_xor(v1, off);
            const int   oi = __shfl_xor(i1, off);
            if (ov > v1 || (ov == v1 && oi < i1)) { v1 = ov; i1 = oi; }
        }
        float v2 = (lane == i1) ? -INFINITY : l; int i2 = lane;
#pragma unroll
        for (int off = 32; off >= 1; off >>= 1) {
            const float ov = __shfl_xor(v2, off);
            const int   oi = __shfl_xor(i2, off);
            if (ov > v2 || (ov == v2 && oi < i2)) { v2 = ov; i2 = oi; }
        }
        float v3 = (lane == i1 || lane == i2) ? -INFINITY : l; int i3 = lane;
#pragma unroll
        for (int off = 32; off >= 1; off >>= 1) {
            const float ov = __shfl_xor(v3, off);
            const int   oi = __shfl_xor(i3, off);
            if (ov > v3 || (ov == v3 && oi < i3)) { v3 = ov; i3 = oi; }
        }

        const float p = expf(l - v1);
        float s = p;
#pragma unroll
        for (int off = 32; off >= 1; off >>= 1) s += __shfl_xor(s, off);

        int iA = i1, iB = i2;
        if ((v1 - v2) < REFINE_TAU || (v2 - v3) < REFINE_TAU) {
            const float* __restrict__ xrow = x + (size_t)tok * DDIM;
            double La = dot_f64(xrow, W + (size_t)i1 * DDIM, lane);
            double Lb = dot_f64(xrow, W + (size_t)i2 * DDIM, lane);
            double Lc = dot_f64(xrow, W + (size_t)i3 * DDIM, lane);
            int ia = i1, ib = i2, ic = i3;
            if (!better(La, ia, Lb, ib)) { double tv = La; La = Lb; Lb = tv; int ti = ia; ia = ib; ib = ti; }
            if (!better(Lb, ib, Lc, ic)) { double tv = Lb; Lb = Lc; Lc = tv; int ti = ib; ib = ic; ic = ti; }
            if (!better(La, ia, Lb, ib)) { double tv = La; La = Lb; Lb = tv; int ti = ia; ia = ib; ib = ti; }
            iA = ia; iB = ib;
        }

        const float pA = __shfl(p, iA);
        const float pB = __shfl(p, iB);
        const float pa = pA / s;
        const float pb = pB / s;
        const float inv = 1.0f / (pa + pb + 1e-9f);

        if (lane == 0) {
            const size_t tg2 = (size_t)tok;
            outw[tg2 * 2]     = pa * inv;
            outw[tg2 * 2 + 1] = pb * inv;
            outi[tg2 * 2]     = (float)iA;
            outi[tg2 * 2 + 1] = (float)iB;
        }
    }
}

extern "C" void kernel_launch(void* const* d_in, const int* in_sizes, int n_in,
                              void* d_out, int out_size, void* d_ws, size_t ws_size,
                              hipStream_t stream) {
    const float* x = (const float*)d_in[0];
    const float* W = (const float*)d_in[1];
    float* out    = (float*)d_out;
    float* logits = (float*)d_ws;                       // 16384*64*4 = 4 MB

    gate_gemm<<<T_TOKENS / BLK_TOK, 256, 0, stream>>>(x, W, logits);
    router_epilogue<<<T_TOKENS / 32, 256, 0, stream>>>(logits, x, W, out);
}

// Round 5
// 98.636 us; speedup vs baseline: 2.1913x; 1.0922x over previous
//
#include <hip/hip_runtime.h>
#include <hip/hip_bf16.h>
#include <math.h>

#define T_TOKENS 16384
#define DDIM 2048
#define NEXP 64
#define KC 64
#define NCH (DDIM / KC)            // 32 chunks
#define BLK_TOK 64
#define NBLK (T_TOKENS / BLK_TOK)  // 256 blocks
#define REFINE_TAU 4e-3f
#define LGS 66                     // logits LDS stride (floats) — conflict-free rd/wr

typedef short bf16x8 __attribute__((ext_vector_type(8)));
typedef float f32x4 __attribute__((ext_vector_type(4)));

__device__ __forceinline__ short bf16hi(float f) {
    __hip_bfloat16 h = __float2bfloat16(f);       // RNE
    return *reinterpret_cast<short*>(&h);
}
__device__ __forceinline__ float bf16up(short s) {
    __hip_bfloat16 h = *reinterpret_cast<__hip_bfloat16*>(&s);
    return __bfloat162float(h);
}

// ---------------- Kernel 0: W -> B-fragment panels (hi/lo), coalesced-for-MFMA ----------------
// For W element (row r, k): g=r>>4, ks=k>>5, lane=((k>>3)&3)*16 + (r&15), e=k&7.
// panel[g][ks][lane][e] shorts. A wave-load of panel[g][ks][lane*8..+8] IS the B-frag.
__global__ __launch_bounds__(256)
void prep_w(const float* __restrict__ W, short* __restrict__ ph, short* __restrict__ pl) {
    const int t  = blockIdx.x * 256 + threadIdx.x;   // 0..16383
    const int r  = t >> 8;                           // 64 rows, 256 thr/row
    const int kc = (t & 255) * 8;
    const float* wp = &W[(size_t)r * DDIM + kc];
    const float4 a = *(const float4*)wp;
    const float4 b = *(const float4*)(wp + 4);
    const float f[8] = { a.x, a.y, a.z, a.w, b.x, b.y, b.z, b.w };
    bf16x8 h, l;
#pragma unroll
    for (int j = 0; j < 8; ++j) {
        const short hh = bf16hi(f[j]);
        h[j] = hh;
        l[j] = bf16hi(f[j] - bf16up(hh));
    }
    const int g = r >> 4, ks = kc >> 5;
    const int lane = (((kc >> 3) & 3) << 4) + (r & 15);
    const size_t idx = ((((size_t)g * (DDIM / 32) + ks) * 64) + lane) * 8;
    *(bf16x8*)&ph[idx] = h;
    *(bf16x8*)&pl[idx] = l;
}

// ---------------- Kernel 1: fused gate GEMM + softmax/top-2 ----------------
__device__ __forceinline__ bool better(double va, int ia, double vb, int ib) {
    return (va > vb) || (va == vb && ia < ib);
}
__device__ __forceinline__ double dot_f64(const float* __restrict__ xrow,
                                          const float* __restrict__ wr, int lane) {
    double sd = 0.0;
    for (int d = lane; d < DDIM; d += 64)
        sd = fma((double)xrow[d], (double)wr[d], sd);
#pragma unroll
    for (int off = 32; off >= 1; off >>= 1) sd += __shfl_xor(sd, off);
    return sd;
}

#define LOADX(slot, c) do { \
    const float* p_ = xsrc + (size_t)(c) * KC; \
    slot[0] = *(const float4*)p_; \
    slot[1] = *(const float4*)(p_ + 4); \
} while (0)

#define COMMITX(slot) do { \
    const float f_[8] = { slot[0].x, slot[0].y, slot[0].z, slot[0].w, \
                          slot[1].x, slot[1].y, slot[1].z, slot[1].w }; \
    bf16x8 h_, l_; \
    _Pragma("unroll") \
    for (int j_ = 0; j_ < 8; ++j_) { \
        const short s_ = bf16hi(f_[j_]); \
        h_[j_] = s_; \
        l_[j_] = bf16hi(f_[j_] - bf16up(s_)); \
    } \
    *(bf16x8*)((char*)xh + xb) = h_; \
    *(bf16x8*)((char*)xl + xb) = l_; \
} while (0)

#define LOADB(B, c) do { \
    _Pragma("unroll") \
    for (int ks_ = 0; ks_ < 2; ++ks_) { \
        _Pragma("unroll") \
        for (int n_ = 0; n_ < 2; ++n_) { \
            const size_t ib_ = ((((size_t)(eg * 2 + n_) * (DDIM / 32)) + ((c) * 2 + ks_)) * 64 + lane) * 8; \
            B[ks_ * 4 + n_ * 2]     = *(const bf16x8*)&ph[ib_]; \
            B[ks_ * 4 + n_ * 2 + 1] = *(const bf16x8*)&pl[ib_]; \
        } \
    } \
} while (0)

#define COMPUTE(B) do { \
    _Pragma("unroll") \
    for (int ks_ = 0; ks_ < 2; ++ks_) { \
        const int ar_ = tg * 16 + (lane & 15); \
        const int ab_ = ((ar_ * 128 + ks_ * 64 + (lane >> 4) * 16) ^ ((ar_ & 7) << 4)); \
        const bf16x8 ah_ = *(const bf16x8*)((char*)xh + ab_); \
        const bf16x8 al_ = *(const bf16x8*)((char*)xl + ab_); \
        _Pragma("unroll") \
        for (int n_ = 0; n_ < 2; ++n_) { \
            acc[n_] = __builtin_amdgcn_mfma_f32_16x16x32_bf16(ah_, B[ks_ * 4 + n_ * 2],     acc[n_], 0, 0, 0); \
            acc[n_] = __builtin_amdgcn_mfma_f32_16x16x32_bf16(ah_, B[ks_ * 4 + n_ * 2 + 1], acc[n_], 0, 0, 0); \
            acc[n_] = __builtin_amdgcn_mfma_f32_16x16x32_bf16(al_, B[ks_ * 4 + n_ * 2],     acc[n_], 0, 0, 0); \
        } \
    } \
} while (0)

__global__ __launch_bounds__(512, 2)
void gate_fused(const float* __restrict__ x,
                const short* __restrict__ ph,
                const short* __restrict__ pl,
                const float* __restrict__ W,
                float* __restrict__ out) {
    __shared__ short xh[BLK_TOK * KC];     // 8 KB, XOR-swizzled rows of 128 B
    __shared__ short xl[BLK_TOK * KC];     // 8 KB
    __shared__ float lg[BLK_TOK * LGS];    // 16.5 KB logits

    const int tid  = threadIdx.x;
    const int lane = tid & 63;
    const int w    = tid >> 6;     // 0..7
    const int tg   = w >> 1;       // token group 0..3 (16 tokens each)
    const int eg   = w & 1;        // expert group 0..1 (32 experts each)
    const int tokb = blockIdx.x * BLK_TOK;

    // x staging map: thread -> (row, 8-float segment)
    const int srow = tid >> 3;          // 0..63
    const int skf  = (tid & 7) * 8;     // float offset within 64-float chunk row
    const float* xsrc = x + (size_t)(tokb + srow) * DDIM + skf;
    const int xb = ((srow * 128 + skf * 2) ^ ((srow & 7) << 4));

    f32x4 acc[2] = { {0.f, 0.f, 0.f, 0.f}, {0.f, 0.f, 0.f, 0.f} };
    float4 xrA[2], xrB[2];
    bf16x8 BA[8], BB[8];

    // prologue: chunk 0 + 1 x loads, chunk 0 B frags
    LOADX(xrA, 0);
    LOADX(xrB, 1);
    LOADB(BA, 0);

#pragma unroll 1
    for (int i = 0; i < 16; ++i) {
        const int c0 = 2 * i;
        // ---- even chunk c0 (slot A) ----
        COMMITX(xrA);                       // waits xrA (issued a full iter ago)
        if (i < 15) LOADX(xrA, c0 + 2);     // reissue immediately -> ~full-iter latency cover
        LOADB(BB, c0 + 1);                  // L2 frags for odd chunk
        __syncthreads();
        COMPUTE(BA);
        __syncthreads();
        // ---- odd chunk c0+1 (slot B) ----
        COMMITX(xrB);
        if (i < 15) { LOADX(xrB, c0 + 3); LOADB(BA, c0 + 2); }
        __syncthreads();
        COMPUTE(BB);
        __syncthreads();
    }

    // ---- logits -> LDS (C layout: col=lane&15, row=(lane>>4)*4+j; m89-verified) ----
#pragma unroll
    for (int n = 0; n < 2; ++n)
#pragma unroll
        for (int j = 0; j < 4; ++j) {
            const int trow = tg * 16 + ((lane >> 4) << 2) + j;
            const int ecol = eg * 32 + n * 16 + (lane & 15);
            lg[trow * LGS + ecol] = acc[n][j];
        }
    __syncthreads();

    // ---- fused epilogue: each wave owns 8 tokens ----
    float* __restrict__ outw = out;
    float* __restrict__ outi = out + (size_t)T_TOKENS * 2;

#pragma unroll 1
    for (int t = 0; t < 8; ++t) {
        const int lt  = w * 8 + t;
        const int tok = tokb + lt;
        const float l = lg[lt * LGS + lane];

        float v1 = l; int i1 = lane;
#pragma unroll
        for (int off = 32; off >= 1; off >>= 1) {
            const float ov = __shfl_xor(v1, off);
            const int   oi = __shfl_xor(i1, off);
            if (ov > v1 || (ov == v1 && oi < i1)) { v1 = ov; i1 = oi; }
        }
        float v2 = (lane == i1) ? -INFINITY : l; int i2 = lane;
#pragma unroll
        for (int off = 32; off >= 1; off >>= 1) {
            const float ov = __shfl_xor(v2, off);
            const int   oi = __shfl_xor(i2, off);
            if (ov > v2 || (ov == v2 && oi < i2)) { v2 = ov; i2 = oi; }
        }
        float v3 = (lane == i1 || lane == i2) ? -INFINITY : l; int i3 = lane;
#pragma unroll
        for (int off = 32; off >= 1; off >>= 1) {
            const float ov = __shfl_xor(v3, off);
            const int   oi = __shfl_xor(i3, off);
            if (ov > v3 || (ov == v3 && oi < i3)) { v3 = ov; i3 = oi; }
        }

        const float p = expf(l - v1);
        float s = p;
#pragma unroll
        for (int off = 32; off >= 1; off >>= 1) s += __shfl_xor(s, off);

        int iA = i1, iB = i2;
        if ((v1 - v2) < REFINE_TAU || (v2 - v3) < REFINE_TAU) {
            const float* __restrict__ xrow = x + (size_t)tok * DDIM;
            double La = dot_f64(xrow, W + (size_t)i1 * DDIM, lane);
            double Lb = dot_f64(xrow, W + (size_t)i2 * DDIM, lane);
            double Lc = dot_f64(xrow, W + (size_t)i3 * DDIM, lane);
            int ia = i1, ib = i2, ic = i3;
            if (!better(La, ia, Lb, ib)) { double tv = La; La = Lb; Lb = tv; int ti = ia; ia = ib; ib = ti; }
            if (!better(Lb, ib, Lc, ic)) { double tv = Lb; Lb = Lc; Lc = tv; int ti = ib; ib = ic; ic = ti; }
            if (!better(La, ia, Lb, ib)) { double tv = La; La = Lb; Lb = tv; int ti = ia; ia = ib; ib = ti; }
            iA = ia; iB = ib;
        }

        const float pA = __shfl(p, iA);
        const float pB = __shfl(p, iB);
        const float pa = pA / s;
        const float pb = pB / s;
        const float inv = 1.0f / (pa + pb + 1e-9f);

        if (lane == 0) {
            const size_t tg2 = (size_t)tok;
            outw[tg2 * 2]     = pa * inv;
            outw[tg2 * 2 + 1] = pb * inv;
            outi[tg2 * 2]     = (float)iA;
            outi[tg2 * 2 + 1] = (float)iB;
        }
    }
}

extern "C" void kernel_launch(void* const* d_in, const int* in_sizes, int n_in,
                              void* d_out, int out_size, void* d_ws, size_t ws_size,
                              hipStream_t stream) {
    const float* x = (const float*)d_in[0];
    const float* W = (const float*)d_in[1];
    float* out = (float*)d_out;

    short* ph = (short*)d_ws;                          // 256 KB hi panel
    short* pl = ph + (size_t)NEXP * DDIM;              // 256 KB lo panel

    prep_w<<<NEXP * DDIM / 8 / 256, 256, 0, stream>>>(W, ph, pl);
    gate_fused<<<NBLK, 512, 0, stream>>>(x, ph, pl, W, out);
}

// Round 6
// 91.465 us; speedup vs baseline: 2.3631x; 1.0784x over previous
//
#include <hip/hip_runtime.h>
#include <hip/hip_bf16.h>
#include <math.h>

#define T_TOKENS 16384
#define DDIM 2048
#define NEXP 64
#define REFINE_TAU 4e-3f
#define KSPLIT 4
#define KPW (DDIM / KSPLIT)       // 512 k per wave
#define NCHW (KPW / 32)           // 16 chunks of 32-k per wave
#define BLK_TOK 16
#define NBLK (T_TOKENS / BLK_TOK) // 1024 blocks

typedef short bf16x8 __attribute__((ext_vector_type(8)));
typedef float f32x4 __attribute__((ext_vector_type(4)));

__device__ __forceinline__ short bf16hi(float f) {
    __hip_bfloat16 h = __float2bfloat16(f);       // RNE
    return *reinterpret_cast<short*>(&h);
}
__device__ __forceinline__ float bf16up(short s) {
    __hip_bfloat16 h = *reinterpret_cast<__hip_bfloat16*>(&s);
    return __bfloat162float(h);
}

// ---------------- Kernel 0: W -> fragment-ordered panels (hi/lo) ----------------
// Element (expert r, k) -> panel[((g*(DDIM/32) + ks)*64 + lane)*8 + j] with
// g=r>>4, ks=k>>5, lane=((k>>3)&3)*16 + (r&15), j=k&7.  (R4/R5-verified mapping;
// same layout serves as the MFMA A-operand fragment here.)
__global__ __launch_bounds__(256)
void prep_w(const float* __restrict__ W, short* __restrict__ ph, short* __restrict__ pl) {
    const int t  = blockIdx.x * 256 + threadIdx.x;   // 0..16383
    const int r  = t >> 8;                           // expert row
    const int kc = (t & 255) * 8;
    const float* wp = &W[(size_t)r * DDIM + kc];
    const float4 a = *(const float4*)wp;
    const float4 b = *(const float4*)(wp + 4);
    const float f[8] = { a.x, a.y, a.z, a.w, b.x, b.y, b.z, b.w };
    bf16x8 h, l;
#pragma unroll
    for (int j = 0; j < 8; ++j) {
        const short hh = bf16hi(f[j]);
        h[j] = hh;
        l[j] = bf16hi(f[j] - bf16up(hh));
    }
    const int g = r >> 4, ks = kc >> 5;
    const int lane = (((kc >> 3) & 3) << 4) + (r & 15);
    const size_t idx = ((((size_t)g * (DDIM / 32) + ks) * 64) + lane) * 8;
    *(bf16x8*)&ph[idx] = h;
    *(bf16x8*)&pl[idx] = l;
}

// ---------------- Kernel 1: barrier-free gate GEMM + fused top-2 ----------------
__device__ __forceinline__ bool better(double va, int ia, double vb, int ib) {
    return (va > vb) || (va == vb && ia < ib);
}
__device__ __forceinline__ double dot_f64(const float* __restrict__ xrow,
                                          const float* __restrict__ wr, int lane) {
    double sd = 0.0;
    for (int d = lane; d < DDIM; d += 64)
        sd = fma((double)xrow[d], (double)wr[d], sd);
#pragma unroll
    for (int off = 32; off >= 1; off >>= 1) sd += __shfl_xor(sd, off);
    return sd;
}

#define LOADX(slot, c) do { \
    const float* p_ = xsrc + (size_t)(c) * 32; \
    xr[slot][0] = *(const float4*)p_; \
    xr[slot][1] = *(const float4*)(p_ + 4); \
} while (0)

#define LOADP(buf, c) do { \
    _Pragma("unroll") \
    for (int mt_ = 0; mt_ < 4; ++mt_) { \
        const size_t ib_ = pbase + (size_t)(c) * 512 + (size_t)mt_ * ((DDIM / 32) * 512); \
        pa[buf][mt_]     = *(const bf16x8*)&ph[ib_]; \
        pa[buf][4 + mt_] = *(const bf16x8*)&pl[ib_]; \
    } \
} while (0)

#define CHUNK(slot, buf) do { \
    const float f_[8] = { xr[slot][0].x, xr[slot][0].y, xr[slot][0].z, xr[slot][0].w, \
                          xr[slot][1].x, xr[slot][1].y, xr[slot][1].z, xr[slot][1].w }; \
    bf16x8 bh_, bl_; \
    _Pragma("unroll") \
    for (int j_ = 0; j_ < 8; ++j_) { \
        const short s_ = bf16hi(f_[j_]); \
        bh_[j_] = s_; \
        bl_[j_] = bf16hi(f_[j_] - bf16up(s_)); \
    } \
    _Pragma("unroll") \
    for (int mt_ = 0; mt_ < 4; ++mt_) { \
        acc[mt_] = __builtin_amdgcn_mfma_f32_16x16x32_bf16(pa[buf][mt_],     bh_, acc[mt_], 0, 0, 0); \
        acc[mt_] = __builtin_amdgcn_mfma_f32_16x16x32_bf16(pa[buf][4 + mt_], bh_, acc[mt_], 0, 0, 0); \
        acc[mt_] = __builtin_amdgcn_mfma_f32_16x16x32_bf16(pa[buf][mt_],     bl_, acc[mt_], 0, 0, 0); \
    } \
} while (0)

__global__ __launch_bounds__(256, 4)
void gate_fused(const float* __restrict__ x,
                const short* __restrict__ ph,
                const short* __restrict__ pl,
                const float* __restrict__ W,
                float* __restrict__ out) {
    __shared__ float part[KSPLIT][NEXP][17];   // 17.4 KB, deterministic reduction buffer

    const int tid  = threadIdx.x;
    const int lane = tid & 63;
    const int w    = tid >> 6;                 // K-slice 0..3
    const int tokb = blockIdx.x * BLK_TOK;

    // x source: token tokb+(lane&15), k base = w*512 + (lane>>4)*8  (B-frag layout)
    const float* xsrc = x + (size_t)(tokb + (lane & 15)) * DDIM
                          + (size_t)w * KPW + ((lane >> 4) << 3);
    // panel base for this wave's K-slice (chunk stride 512 shorts, mt stride 32768)
    const size_t pbase = ((size_t)(w * NCHW) * 64 + (size_t)lane) * 8;

    f32x4 acc[4] = { {0,0,0,0}, {0,0,0,0}, {0,0,0,0}, {0,0,0,0} };
    float4 xr[3][2];
    bf16x8 pa[2][8];

    // prologue: 3-deep x prefetch, 1-deep panel prefetch
    LOADX(0, 0); LOADX(1, 1); LOADX(2, 2);
    LOADP(0, 0);

#pragma unroll
    for (int c = 0; c < NCHW; ++c) {
        if (c + 1 < NCHW) LOADP((c + 1) & 1, c + 1);
        CHUNK(c % 3, c & 1);
        if (c + 3 < NCHW) LOADX((c + 3) % 3, c + 3);
    }

    // ---- partials -> LDS (C layout: col=lane&15=token, row=(lane>>4)*4+j=expert-in-tile) ----
#pragma unroll
    for (int mt = 0; mt < 4; ++mt)
#pragma unroll
        for (int j = 0; j < 4; ++j) {
            const int e = mt * 16 + ((lane >> 4) << 2) + j;
            part[w][e][lane & 15] = acc[mt][j];
        }
    __syncthreads();

    // ---- epilogue: wave w owns 4 tokens; fixed-order K reduction (deterministic) ----
    float* __restrict__ outw = out;
    float* __restrict__ outi = out + (size_t)T_TOKENS * 2;

#pragma unroll 1
    for (int t = 0; t < 4; ++t) {
        const int lt  = w * 4 + t;
        const int tok = tokb + lt;
        const float l = ((part[0][lane][lt] + part[1][lane][lt])
                       + (part[2][lane][lt] + part[3][lane][lt]));

        float v1 = l; int i1 = lane;
#pragma unroll
        for (int off = 32; off >= 1; off >>= 1) {
            const float ov = __shfl_xor(v1, off);
            const int   oi = __shfl_xor(i1, off);
            if (ov > v1 || (ov == v1 && oi < i1)) { v1 = ov; i1 = oi; }
        }
        float v2 = (lane == i1) ? -INFINITY : l; int i2 = lane;
#pragma unroll
        for (int off = 32; off >= 1; off >>= 1) {
            const float ov = __shfl_xor(v2, off);
            const int   oi = __shfl_xor(i2, off);
            if (ov > v2 || (ov == v2 && oi < i2)) { v2 = ov; i2 = oi; }
        }
        float v3 = (lane == i1 || lane == i2) ? -INFINITY : l; int i3 = lane;
#pragma unroll
        for (int off = 32; off >= 1; off >>= 1) {
            const float ov = __shfl_xor(v3, off);
            const int   oi = __shfl_xor(i3, off);
            if (ov > v3 || (ov == v3 && oi < i3)) { v3 = ov; i3 = oi; }
        }

        const float p = expf(l - v1);
        float s = p;
#pragma unroll
        for (int off = 32; off >= 1; off >>= 1) s += __shfl_xor(s, off);

        int iA = i1, iB = i2;
        if ((v1 - v2) < REFINE_TAU || (v2 - v3) < REFINE_TAU) {
            const float* __restrict__ xrow = x + (size_t)tok * DDIM;
            double La = dot_f64(xrow, W + (size_t)i1 * DDIM, lane);
            double Lb = dot_f64(xrow, W + (size_t)i2 * DDIM, lane);
            double Lc = dot_f64(xrow, W + (size_t)i3 * DDIM, lane);
            int ia = i1, ib = i2, ic = i3;
            if (!better(La, ia, Lb, ib)) { double tv = La; La = Lb; Lb = tv; int ti = ia; ia = ib; ib = ti; }
            if (!better(Lb, ib, Lc, ic)) { double tv = Lb; Lb = Lc; Lc = tv; int ti = ib; ib = ic; ic = ti; }
            if (!better(La, ia, Lb, ib)) { double tv = La; La = Lb; Lb = tv; int ti = ia; ia = ib; ib = ti; }
            iA = ia; iB = ib;
        }

        const float pA = __shfl(p, iA);
        const float pB = __shfl(p, iB);
        const float pa_ = pA / s;
        const float pb_ = pB / s;
        const float inv = 1.0f / (pa_ + pb_ + 1e-9f);

        if (lane == 0) {
            const size_t tg2 = (size_t)tok;
            outw[tg2 * 2]     = pa_ * inv;
            outw[tg2 * 2 + 1] = pb_ * inv;
            outi[tg2 * 2]     = (float)iA;
            outi[tg2 * 2 + 1] = (float)iB;
        }
    }
}

extern "C" void kernel_launch(void* const* d_in, const int* in_sizes, int n_in,
                              void* d_out, int out_size, void* d_ws, size_t ws_size,
                              hipStream_t stream) {
    const float* x = (const float*)d_in[0];
    const float* W = (const float*)d_in[1];
    float* out = (float*)d_out;

    short* ph = (short*)d_ws;                          // 256 KB hi panel
    short* pl = ph + (size_t)NEXP * DDIM;              // 256 KB lo panel

    prep_w<<<NEXP * DDIM / 8 / 256, 256, 0, stream>>>(W, ph, pl);
    gate_fused<<<NBLK, 256, 0, stream>>>(x, ph, pl, W, out);
}

// Round 7
// 89.298 us; speedup vs baseline: 2.4205x; 1.0243x over previous
//
#include <hip/hip_runtime.h>
#include <hip/hip_bf16.h>
#include <math.h>

#define T_TOKENS 16384
#define DDIM 2048
#define NEXP 64
#define REFINE_TAU 4e-3f
#define KSPLIT 8
#define KPW (DDIM / KSPLIT)       // 256 k per wave
#define NCHW (KPW / 32)           // 8 chunks of 32-k per wave
#define BLK_TOK 16
#define NBLK (T_TOKENS / BLK_TOK) // 1024 blocks

typedef short bf16x8 __attribute__((ext_vector_type(8)));
typedef float f32x4 __attribute__((ext_vector_type(4)));

__device__ __forceinline__ short bf16hi(float f) {
    __hip_bfloat16 h = __float2bfloat16(f);       // RNE
    return *reinterpret_cast<short*>(&h);
}
__device__ __forceinline__ float bf16up(short s) {
    __hip_bfloat16 h = *reinterpret_cast<__hip_bfloat16*>(&s);
    return __bfloat162float(h);
}

// ---------------- Kernel 0: W -> fragment-ordered panels (hi/lo) ----------------
// Element (expert r, k) -> panel[((g*(DDIM/32) + ks)*64 + lane)*8 + j] with
// g=r>>4, ks=k>>5, lane=((k>>3)&3)*16 + (r&15), j=k&7.  (R4-R6-verified mapping.)
__global__ __launch_bounds__(256)
void prep_w(const float* __restrict__ W, short* __restrict__ ph, short* __restrict__ pl) {
    const int t  = blockIdx.x * 256 + threadIdx.x;   // 0..16383
    const int r  = t >> 8;                           // expert row
    const int kc = (t & 255) * 8;
    const float* wp = &W[(size_t)r * DDIM + kc];
    const float4 a = *(const float4*)wp;
    const float4 b = *(const float4*)(wp + 4);
    const float f[8] = { a.x, a.y, a.z, a.w, b.x, b.y, b.z, b.w };
    bf16x8 h, l;
#pragma unroll
    for (int j = 0; j < 8; ++j) {
        const short hh = bf16hi(f[j]);
        h[j] = hh;
        l[j] = bf16hi(f[j] - bf16up(hh));
    }
    const int g = r >> 4, ks = kc >> 5;
    const int lane = (((kc >> 3) & 3) << 4) + (r & 15);
    const size_t idx = ((((size_t)g * (DDIM / 32) + ks) * 64) + lane) * 8;
    *(bf16x8*)&ph[idx] = h;
    *(bf16x8*)&pl[idx] = l;
}

// ---------------- Kernel 1: barrier-free gate GEMM + fused top-2 ----------------
__device__ __forceinline__ bool better(double va, int ia, double vb, int ib) {
    return (va > vb) || (va == vb && ia < ib);
}
__device__ __forceinline__ double dot_f64(const float* __restrict__ xrow,
                                          const float* __restrict__ wr, int lane) {
    double sd = 0.0;
    for (int d = lane; d < DDIM; d += 64)
        sd = fma((double)xrow[d], (double)wr[d], sd);
#pragma unroll
    for (int off = 32; off >= 1; off >>= 1) sd += __shfl_xor(sd, off);
    return sd;
}

#define LOADX(slot, c) do { \
    const float* p_ = xsrc + (size_t)(c) * 32; \
    xr[slot][0] = *(const float4*)p_; \
    xr[slot][1] = *(const float4*)(p_ + 4); \
} while (0)

#define LOADP(buf, c) do { \
    _Pragma("unroll") \
    for (int mt_ = 0; mt_ < 4; ++mt_) { \
        const size_t ib_ = pbase + (size_t)(c) * 512 + (size_t)mt_ * ((DDIM / 32) * 512); \
        pa[buf][mt_]     = *(const bf16x8*)&ph[ib_]; \
        pa[buf][4 + mt_] = *(const bf16x8*)&pl[ib_]; \
    } \
} while (0)

#define CHUNK(slot, buf) do { \
    const float f_[8] = { xr[slot][0].x, xr[slot][0].y, xr[slot][0].z, xr[slot][0].w, \
                          xr[slot][1].x, xr[slot][1].y, xr[slot][1].z, xr[slot][1].w }; \
    bf16x8 bh_, bl_; \
    _Pragma("unroll") \
    for (int j_ = 0; j_ < 8; ++j_) { \
        const short s_ = bf16hi(f_[j_]); \
        bh_[j_] = s_; \
        bl_[j_] = bf16hi(f_[j_] - bf16up(s_)); \
    } \
    _Pragma("unroll") \
    for (int mt_ = 0; mt_ < 4; ++mt_) { \
        acc[mt_] = __builtin_amdgcn_mfma_f32_16x16x32_bf16(pa[buf][mt_],     bh_, acc[mt_], 0, 0, 0); \
        acc[mt_] = __builtin_amdgcn_mfma_f32_16x16x32_bf16(pa[buf][4 + mt_], bh_, acc[mt_], 0, 0, 0); \
        acc[mt_] = __builtin_amdgcn_mfma_f32_16x16x32_bf16(pa[buf][mt_],     bl_, acc[mt_], 0, 0, 0); \
    } \
} while (0)

__global__ __launch_bounds__(512, 8)
void gate_fused(const float* __restrict__ x,
                const short* __restrict__ ph,
                const short* __restrict__ pl,
                const float* __restrict__ W,
                float* __restrict__ out) {
    __shared__ float part[KSPLIT][NEXP][17];   // 34.8 KB -> exactly 4 blocks/CU

    const int tid  = threadIdx.x;
    const int lane = tid & 63;
    const int w    = tid >> 6;                 // K-slice 0..7
    const int tokb = blockIdx.x * BLK_TOK;

    // x source: token tokb+(lane&15), k base = w*256 + (lane>>4)*8  (B-frag layout)
    const float* xsrc = x + (size_t)(tokb + (lane & 15)) * DDIM
                          + (size_t)w * KPW + ((lane >> 4) << 3);
    // panel base for this wave's K-slice (chunk stride 512 shorts, mt stride 32768)
    const size_t pbase = ((size_t)(w * NCHW) * 64 + (size_t)lane) * 8;

    f32x4 acc[4] = { {0,0,0,0}, {0,0,0,0}, {0,0,0,0}, {0,0,0,0} };
    float4 xr[3][2];
    bf16x8 pa[2][8];

    // prologue: 3-deep x prefetch, 1-deep panel prefetch
    LOADX(0, 0); LOADX(1, 1); LOADX(2, 2);
    LOADP(0, 0);

#pragma unroll
    for (int c = 0; c < NCHW; ++c) {
        if (c + 1 < NCHW) LOADP((c + 1) & 1, c + 1);
        CHUNK(c % 3, c & 1);
        if (c + 3 < NCHW) LOADX((c + 3) % 3, c + 3);
    }

    // ---- partials -> LDS (C layout: col=lane&15=token, row=(lane>>4)*4+j=expert-in-tile) ----
#pragma unroll
    for (int mt = 0; mt < 4; ++mt)
#pragma unroll
        for (int j = 0; j < 4; ++j) {
            const int e = mt * 16 + ((lane >> 4) << 2) + j;
            part[w][e][lane & 15] = acc[mt][j];
        }
    __syncthreads();

    // ---- epilogue: wave w owns 2 tokens; fixed-order K reduction (deterministic) ----
    float* __restrict__ outw = out;
    float* __restrict__ outi = out + (size_t)T_TOKENS * 2;

#pragma unroll 1
    for (int t = 0; t < 2; ++t) {
        const int lt  = w * 2 + t;
        const int tok = tokb + lt;
        const float l = (((part[0][lane][lt] + part[1][lane][lt])
                        + (part[2][lane][lt] + part[3][lane][lt]))
                       + ((part[4][lane][lt] + part[5][lane][lt])
                        + (part[6][lane][lt] + part[7][lane][lt])));

        float v1 = l; int i1 = lane;
#pragma unroll
        for (int off = 32; off >= 1; off >>= 1) {
            const float ov = __shfl_xor(v1, off);
            const int   oi = __shfl_xor(i1, off);
            if (ov > v1 || (ov == v1 && oi < i1)) { v1 = ov; i1 = oi; }
        }
        float v2 = (lane == i1) ? -INFINITY : l; int i2 = lane;
#pragma unroll
        for (int off = 32; off >= 1; off >>= 1) {
            const float ov = __shfl_xor(v2, off);
            const int   oi = __shfl_xor(i2, off);
            if (ov > v2 || (ov == v2 && oi < i2)) { v2 = ov; i2 = oi; }
        }
        float v3 = (lane == i1 || lane == i2) ? -INFINITY : l; int i3 = lane;
#pragma unroll
        for (int off = 32; off >= 1; off >>= 1) {
            const float ov = __shfl_xor(v3, off);
            const int   oi = __shfl_xor(i3, off);
            if (ov > v3 || (ov == v3 && oi < i3)) { v3 = ov; i3 = oi; }
        }

        const float p = expf(l - v1);
        float s = p;
#pragma unroll
        for (int off = 32; off >= 1; off >>= 1) s += __shfl_xor(s, off);

        int iA = i1, iB = i2;
        if ((v1 - v2) < REFINE_TAU || (v2 - v3) < REFINE_TAU) {
            const float* __restrict__ xrow = x + (size_t)tok * DDIM;
            double La = dot_f64(xrow, W + (size_t)i1 * DDIM, lane);
            double Lb = dot_f64(xrow, W + (size_t)i2 * DDIM, lane);
            double Lc = dot_f64(xrow, W + (size_t)i3 * DDIM, lane);
            int ia = i1, ib = i2, ic = i3;
            if (!better(La, ia, Lb, ib)) { double tv = La; La = Lb; Lb = tv; int ti = ia; ia = ib; ib = ti; }
            if (!better(Lb, ib, Lc, ic)) { double tv = Lb; Lb = Lc; Lc = tv; int ti = ib; ib = ic; ic = ti; }
            if (!better(La, ia, Lb, ib)) { double tv = La; La = Lb; Lb = tv; int ti = ia; ia = ib; ib = ti; }
            iA = ia; iB = ib;
        }

        const float pA = __shfl(p, iA);
        const float pB = __shfl(p, iB);
        const float pa_ = pA / s;
        const float pb_ = pB / s;
        const float inv = 1.0f / (pa_ + pb_ + 1e-9f);

        if (lane == 0) {
            const size_t tg2 = (size_t)tok;
            outw[tg2 * 2]     = pa_ * inv;
            outw[tg2 * 2 + 1] = pb_ * inv;
            outi[tg2 * 2]     = (float)iA;
            outi[tg2 * 2 + 1] = (float)iB;
        }
    }
}

extern "C" void kernel_launch(void* const* d_in, const int* in_sizes, int n_in,
                              void* d_out, int out_size, void* d_ws, size_t ws_size,
                              hipStream_t stream) {
    const float* x = (const float*)d_in[0];
    const float* W = (const float*)d_in[1];
    float* out = (float*)d_out;

    short* ph = (short*)d_ws;                          // 256 KB hi panel
    short* pl = ph + (size_t)NEXP * DDIM;              // 256 KB lo panel

    prep_w<<<NEXP * DDIM / 8 / 256, 256, 0, stream>>>(W, ph, pl);
    gate_fused<<<NBLK, 512, 0, stream>>>(x, ph, pl, W, out);
}